// Round 3
// baseline (277.993 us; speedup 1.0000x reference)
//
#include <hip/hip_runtime.h>
#include <hip/hip_bf16.h>

#define T_NUM_TABLES 26
#define T_NUM_ROWS 50000
#define T_WIDTH 128
#define T_BATCH 4096
#define T_NNZ 20
#define T_NUM_NUM 13
#define T_D_IN (T_NUM_TABLES * T_WIDTH + T_NUM_NUM) /* 3341 */
#define T_DK 3392 /* padded K for layer 1: 3392 = 64*53, multiple of G_BK */

typedef __attribute__((ext_vector_type(4))) float f32x4;
typedef __attribute__((ext_vector_type(8))) short bf16x8;

__device__ __forceinline__ void split_hl(float v, __hip_bfloat16& h, __hip_bfloat16& l) {
  h = __float2bfloat16(v);
  l = __float2bfloat16(v - __bfloat162float(h));
}

// ---------------- gather + pool -> hi/lo bf16 into x[B][DK]
__global__ void pool_v3(const float* __restrict__ tables,
                        const int* __restrict__ cat,
                        __hip_bfloat16* __restrict__ xh,
                        __hip_bfloat16* __restrict__ xl) {
  __shared__ int sidx[2][T_NNZ];
  const int b = blockIdx.x * 2 + threadIdx.y;
  const int t = blockIdx.y;
  const int w = threadIdx.x;
  const int* idx = cat + ((size_t)t * T_BATCH + b) * T_NNZ;
  if (w < T_NNZ) sidx[threadIdx.y][w] = idx[w];
  __syncthreads();
  const float* tb = tables + (size_t)t * T_NUM_ROWS * T_WIDTH;
  float acc = 0.f;
#pragma unroll
  for (int j = 0; j < T_NNZ; ++j) {
    acc += tb[(size_t)sidx[threadIdx.y][j] * T_WIDTH + w];
  }
  __hip_bfloat16 h, l;
  split_hl(acc, h, l);
  size_t o = (size_t)b * T_DK + t * T_WIDTH + w;
  xh[o] = h;
  xl[o] = l;
}

// ---------------- numerical tail + zero padding: cols 3328..3391 (64 cols)
__global__ void numtail_v3(const float* __restrict__ num,
                           __hip_bfloat16* __restrict__ xh,
                           __hip_bfloat16* __restrict__ xl) {
  int i = blockIdx.x * blockDim.x + threadIdx.x; // over BATCH*64
  int b = i >> 6, c = i & 63;
  int col = T_NUM_TABLES * T_WIDTH + c; // 3328 + c, max 3391 = T_DK-1
  float v = (c < T_NUM_NUM) ? num[b * T_NUM_NUM + c] : 0.f;
  __hip_bfloat16 h, l;
  split_hl(v, h, l);
  size_t o = (size_t)b * T_DK + col;
  xh[o] = h;
  xl[o] = l;
}

// ---------------- weight transpose + cast hi/lo: fp32 [K][N] -> bf16 [N][Kp], zero-pad
__global__ void wtrans_v3(const float* __restrict__ in,
                          __hip_bfloat16* __restrict__ outh,
                          __hip_bfloat16* __restrict__ outl,
                          int K, int N, int Kp) {
  __shared__ float tile[32][33];
  int kb = blockIdx.x * 32, nb = blockIdx.y * 32;
  for (int r = threadIdx.y; r < 32; r += 8) {
    int k = kb + r, n = nb + threadIdx.x;
    tile[r][threadIdx.x] = (k < K && n < N) ? in[(size_t)k * N + n] : 0.f;
  }
  __syncthreads();
  for (int r = threadIdx.y; r < 32; r += 8) {
    int n = nb + r, k = kb + threadIdx.x;
    if (n < N && k < Kp) {
      __hip_bfloat16 h, l;
      split_hl(tile[threadIdx.x][r], h, l);
      outh[(size_t)n * Kp + k] = h;
      outl[(size_t)n * Kp + k] = l;
    }
  }
}

// ---------------- hi/lo bf16 MFMA GEMM: C = act(A*Bt^T + bias)
// acc = Ah*Bh + Ah*Bl + Al*Bh (fp32 accum). Requires Kp % 64 == 0.
#define G_BM 128
#define G_BN 64
#define G_BK 64

__global__ __launch_bounds__(256, 2) void gemm_hl_v3(
    const __hip_bfloat16* __restrict__ Ah, const __hip_bfloat16* __restrict__ Al,
    const __hip_bfloat16* __restrict__ Bh, const __hip_bfloat16* __restrict__ Bl,
    const float* __restrict__ bias,
    __hip_bfloat16* __restrict__ Ch, __hip_bfloat16* __restrict__ Cl,
    float* __restrict__ Cf,
    int M, int N, int Kp, int relu) {
  __shared__ char smem[(G_BM * G_BK * 2) * 2 + (G_BN * G_BK * 2) * 2]; // 32K A + 16K B
  char* As_h = smem;
  char* As_l = smem + G_BM * G_BK * 2;
  char* Bs_h = smem + G_BM * G_BK * 4;
  char* Bs_l = Bs_h + G_BN * G_BK * 2;

  const int tid = threadIdx.x;
  const int wave = tid >> 6;
  const int lane = tid & 63;
  const int m0 = blockIdx.x * G_BM;
  const int n0 = blockIdx.y * G_BN;
  const int wr = wave >> 1;
  const int wc = wave & 1;

  f32x4 acc[4][2] = {};
  const size_t strideA = (size_t)Kp * 2; // bytes per row (A and Bt share Kp)

  for (int k0 = 0; k0 < Kp; k0 += G_BK) {
    __syncthreads();
    // ---- stage A tiles (hi+lo): 16 chunks of 1024B, 4/wave each
#pragma unroll
    for (int it = 0; it < 4; ++it) {
      int chunk = wave + it * 4;
      int p = chunk * 1024 + lane * 16;
      int row = p >> 7;
      int colb = p & 127;
      int colb_g = colb ^ ((row & 7) << 4); // inverse-swizzle the SOURCE
      size_t goff = (size_t)(m0 + row) * strideA + (size_t)k0 * 2 + colb_g;
      __builtin_amdgcn_global_load_lds(
          (const __attribute__((address_space(1))) void*)((const char*)Ah + goff),
          (__attribute__((address_space(3))) void*)(As_h + chunk * 1024), 16, 0, 0);
      __builtin_amdgcn_global_load_lds(
          (const __attribute__((address_space(1))) void*)((const char*)Al + goff),
          (__attribute__((address_space(3))) void*)(As_l + chunk * 1024), 16, 0, 0);
    }
    // ---- stage B tiles (hi+lo): 8 chunks, 2/wave each
#pragma unroll
    for (int it = 0; it < 2; ++it) {
      int chunk = wave + it * 4;
      int p = chunk * 1024 + lane * 16;
      int row = p >> 7;
      int colb = p & 127;
      int colb_g = colb ^ ((row & 7) << 4);
      size_t goff = (size_t)(n0 + row) * strideA + (size_t)k0 * 2 + colb_g;
      __builtin_amdgcn_global_load_lds(
          (const __attribute__((address_space(1))) void*)((const char*)Bh + goff),
          (__attribute__((address_space(3))) void*)(Bs_h + chunk * 1024), 16, 0, 0);
      __builtin_amdgcn_global_load_lds(
          (const __attribute__((address_space(1))) void*)((const char*)Bl + goff),
          (__attribute__((address_space(3))) void*)(Bs_l + chunk * 1024), 16, 0, 0);
    }
    __syncthreads();

    // ---- compute: 2 k-steps of 32
#pragma unroll
    for (int ks = 0; ks < 2; ++ks) {
      bf16x8 ah[4], al[4], bh[2], bl[2];
      const int cb = (ks * 32 + ((lane >> 4) * 8)) * 2;
#pragma unroll
      for (int m = 0; m < 4; ++m) {
        int row = wr * 64 + m * 16 + (lane & 15);
        int addr = row * 128 + (cb ^ ((row & 7) << 4)); // swizzled read
        ah[m] = *(const bf16x8*)(As_h + addr);
        al[m] = *(const bf16x8*)(As_l + addr);
      }
#pragma unroll
      for (int n = 0; n < 2; ++n) {
        int row = wc * 32 + n * 16 + (lane & 15);
        int addr = row * 128 + (cb ^ ((row & 7) << 4));
        bh[n] = *(const bf16x8*)(Bs_h + addr);
        bl[n] = *(const bf16x8*)(Bs_l + addr);
      }
#pragma unroll
      for (int m = 0; m < 4; ++m)
#pragma unroll
        for (int n = 0; n < 2; ++n) {
          acc[m][n] = __builtin_amdgcn_mfma_f32_16x16x32_bf16(ah[m], bh[n], acc[m][n], 0, 0, 0);
          acc[m][n] = __builtin_amdgcn_mfma_f32_16x16x32_bf16(ah[m], bl[n], acc[m][n], 0, 0, 0);
          acc[m][n] = __builtin_amdgcn_mfma_f32_16x16x32_bf16(al[m], bh[n], acc[m][n], 0, 0, 0);
        }
    }
  }

  // ---- epilogue: C/D layout col=lane&15, row=(lane>>4)*4+i
#pragma unroll
  for (int m = 0; m < 4; ++m) {
#pragma unroll
    for (int n = 0; n < 2; ++n) {
      int col = n0 + wc * 32 + n * 16 + (lane & 15);
      float bv = bias[col];
#pragma unroll
      for (int i = 0; i < 4; ++i) {
        int row = m0 + wr * 64 + m * 16 + ((lane >> 4) * 4) + i;
        float v = acc[m][n][i] + bv;
        if (relu) v = fmaxf(v, 0.f);
        if (Cf) {
          Cf[(size_t)row * N + col] = v;
        } else {
          __hip_bfloat16 h, l;
          split_hl(v, h, l);
          Ch[(size_t)row * N + col] = h;
          Cl[(size_t)row * N + col] = l;
        }
      }
    }
  }
}

// ---------------- final layer: [B,128] fp32 x W4[128] + b4 -> out[B] fp32
__global__ void final_v3(const float* __restrict__ A3,
                         const float* __restrict__ W4,
                         const float* __restrict__ b4,
                         float* __restrict__ out) {
  int row = blockIdx.x * 4 + (threadIdx.x >> 6);
  int lane = threadIdx.x & 63;
  const float* a = A3 + (size_t)row * 128;
  float s = a[lane * 2] * W4[lane * 2] + a[lane * 2 + 1] * W4[lane * 2 + 1];
#pragma unroll
  for (int off = 32; off > 0; off >>= 1) s += __shfl_down(s, off);
  if (lane == 0) out[row] = s + b4[0];
}

extern "C" void kernel_launch(void* const* d_in, const int* in_sizes, int n_in,
                              void* d_out, int out_size, void* d_ws, size_t ws_size,
                              hipStream_t stream) {
  const float* numerical = (const float*)d_in[0];
  const int* cat = (const int*)d_in[1];
  const float* tables = (const float*)d_in[2];
  const float* W1 = (const float*)d_in[3];
  const float* b1 = (const float*)d_in[4];
  const float* W2 = (const float*)d_in[5];
  const float* b2 = (const float*)d_in[6];
  const float* W3 = (const float*)d_in[7];
  const float* b3 = (const float*)d_in[8];
  const float* W4 = (const float*)d_in[9];
  const float* b4 = (const float*)d_in[10];
  float* out = (float*)d_out;

  char* ws = (char*)d_ws;
  size_t off = 0;
  auto walloc = [&](size_t bytes) -> void* {
    void* p = ws + off;
    off = (off + bytes + 255) & ~(size_t)255;
    return p;
  };
  __hip_bfloat16* xh  = (__hip_bfloat16*)walloc((size_t)T_BATCH * T_DK * 2);
  __hip_bfloat16* xl  = (__hip_bfloat16*)walloc((size_t)T_BATCH * T_DK * 2);
  __hip_bfloat16* w1h = (__hip_bfloat16*)walloc((size_t)512 * T_DK * 2);
  __hip_bfloat16* w1l = (__hip_bfloat16*)walloc((size_t)512 * T_DK * 2);
  __hip_bfloat16* a1h = (__hip_bfloat16*)walloc((size_t)T_BATCH * 512 * 2);
  __hip_bfloat16* a1l = (__hip_bfloat16*)walloc((size_t)T_BATCH * 512 * 2);
  __hip_bfloat16* w2h = (__hip_bfloat16*)walloc((size_t)256 * 512 * 2);
  __hip_bfloat16* w2l = (__hip_bfloat16*)walloc((size_t)256 * 512 * 2);
  __hip_bfloat16* a2h = (__hip_bfloat16*)walloc((size_t)T_BATCH * 256 * 2);
  __hip_bfloat16* a2l = (__hip_bfloat16*)walloc((size_t)T_BATCH * 256 * 2);
  __hip_bfloat16* w3h = (__hip_bfloat16*)walloc((size_t)128 * 256 * 2);
  __hip_bfloat16* w3l = (__hip_bfloat16*)walloc((size_t)128 * 256 * 2);
  float* a3           = (float*)walloc((size_t)T_BATCH * 128 * 4);

  wtrans_v3<<<dim3((T_DK + 31) / 32, 512 / 32), dim3(32, 8), 0, stream>>>(W1, w1h, w1l, T_D_IN, 512, T_DK);
  wtrans_v3<<<dim3(512 / 32, 256 / 32), dim3(32, 8), 0, stream>>>(W2, w2h, w2l, 512, 256, 512);
  wtrans_v3<<<dim3(256 / 32, 128 / 32), dim3(32, 8), 0, stream>>>(W3, w3h, w3l, 256, 128, 256);

  pool_v3<<<dim3(T_BATCH / 2, T_NUM_TABLES), dim3(T_WIDTH, 2), 0, stream>>>(tables, cat, xh, xl);
  numtail_v3<<<(T_BATCH * 64) / 256, 256, 0, stream>>>(numerical, xh, xl);

  gemm_hl_v3<<<dim3(T_BATCH / G_BM, 512 / G_BN), 256, 0, stream>>>(
      xh, xl, w1h, w1l, b1, a1h, a1l, nullptr, T_BATCH, 512, T_DK, 1);
  gemm_hl_v3<<<dim3(T_BATCH / G_BM, 256 / G_BN), 256, 0, stream>>>(
      a1h, a1l, w2h, w2l, b2, a2h, a2l, nullptr, T_BATCH, 256, 512, 1);
  gemm_hl_v3<<<dim3(T_BATCH / G_BM, 128 / G_BN), 256, 0, stream>>>(
      a2h, a2l, w3h, w3l, b3, nullptr, nullptr, a3, T_BATCH, 128, 256, 1);
  final_v3<<<T_BATCH / 4, 256, 0, stream>>>(a3, W4, b4, out);
}

// Round 4
// 254.027 us; speedup vs baseline: 1.0943x; 1.0943x over previous
//
#include <hip/hip_runtime.h>
#include <hip/hip_bf16.h>

#define T_NUM_TABLES 26
#define T_NUM_ROWS 50000
#define T_WIDTH 128
#define T_BATCH 4096
#define T_NNZ 20
#define T_NUM_NUM 13
#define T_DE (T_NUM_TABLES * T_WIDTH) /* 3328 = 64*52: embedding-only K, no padding */

typedef __attribute__((ext_vector_type(4))) float f32x4;
typedef __attribute__((ext_vector_type(8))) short bf16x8;

// ---------------- gather + pool -> bf16 x[B][3328]
__global__ void pool_v4(const float* __restrict__ tables,
                        const int* __restrict__ cat,
                        __hip_bfloat16* __restrict__ xh) {
  __shared__ int sidx[2][T_NNZ];
  const int b = blockIdx.x * 2 + threadIdx.y;
  const int t = blockIdx.y;
  const int w = threadIdx.x;
  const int* idx = cat + ((size_t)t * T_BATCH + b) * T_NNZ;
  if (w < T_NNZ) sidx[threadIdx.y][w] = idx[w];
  __syncthreads();
  const float* tb = tables + (size_t)t * T_NUM_ROWS * T_WIDTH;
  float acc = 0.f;
#pragma unroll
  for (int j = 0; j < T_NNZ; ++j) {
    acc += tb[(size_t)sidx[threadIdx.y][j] * T_WIDTH + w];
  }
  xh[(size_t)b * T_DE + t * T_WIDTH + w] = __float2bfloat16(acc);
}

// ---------------- exact fp32 numerical path: c0[b][n] = b1[n] + sum_j num[b][j]*W1[3328+j][n]
__global__ void numbias_v4(const float* __restrict__ num,
                           const float* __restrict__ W1, // [3341][512]
                           const float* __restrict__ b1,
                           float* __restrict__ c0) {      // [B][512]
  __shared__ float snum[T_NUM_NUM];
  int b = blockIdx.x;
  if (threadIdx.x < T_NUM_NUM) snum[threadIdx.x] = num[b * T_NUM_NUM + threadIdx.x];
  __syncthreads();
#pragma unroll
  for (int rep = 0; rep < 2; ++rep) {
    int n = threadIdx.x + rep * 256;
    float acc = b1[n];
#pragma unroll
    for (int j = 0; j < T_NUM_NUM; ++j)
      acc += snum[j] * W1[(size_t)(T_DE + j) * 512 + n];
    c0[(size_t)b * 512 + n] = acc;
  }
}

// ---------------- weight transpose + cast: fp32 [K][N] (row offset k0) -> bf16 [N][Kc]
__global__ void wtrans_v4(const float* __restrict__ in,
                          __hip_bfloat16* __restrict__ outt,
                          int Kc, int N) {
  __shared__ float tile[32][33];
  int kb = blockIdx.x * 32, nb = blockIdx.y * 32;
  for (int r = threadIdx.y; r < 32; r += 8) {
    int k = kb + r, n = nb + threadIdx.x;
    tile[r][threadIdx.x] = (k < Kc && n < N) ? in[(size_t)k * N + n] : 0.f;
  }
  __syncthreads();
  for (int r = threadIdx.y; r < 32; r += 8) {
    int n = nb + r, k = kb + threadIdx.x;
    if (n < N && k < Kc) outt[(size_t)n * Kc + k] = __float2bfloat16(tile[threadIdx.x][r]);
  }
}

// ---------------- bf16 MFMA GEMM: C = act(A*Bt^T + bias)   (Kp % 64 == 0)
// BM=128, BN=64, BK=64, 4 waves (2x2), per-wave 64x32 (4x2 16x16 frags).
#define G_BM 128
#define G_BN 64
#define G_BK 64

__global__ __launch_bounds__(256, 2) void gemm_v4(
    const __hip_bfloat16* __restrict__ A,   // [M][Kp]
    const __hip_bfloat16* __restrict__ Bt,  // [N][Kp]
    const float* __restrict__ bias1,        // [N] or null
    const float* __restrict__ bias2d,       // [M][N] or null
    __hip_bfloat16* __restrict__ Ch,        // bf16 out (or null)
    float* __restrict__ Cf,                 // fp32 out (or null)
    int M, int N, int Kp, int relu) {
  __shared__ char smem[G_BM * G_BK * 2 + G_BN * G_BK * 2]; // 16K A + 8K B
  char* As = smem;
  char* Bs = smem + G_BM * G_BK * 2;

  const int tid = threadIdx.x;
  const int wave = tid >> 6;
  const int lane = tid & 63;
  const int m0 = blockIdx.x * G_BM;
  const int n0 = blockIdx.y * G_BN;
  const int wr = wave >> 1;
  const int wc = wave & 1;

  f32x4 acc[4][2] = {};
  const size_t strideA = (size_t)Kp * 2;

  for (int k0 = 0; k0 < Kp; k0 += G_BK) {
    __syncthreads();
    // ---- stage A tile: 16 chunks of 1024B, 4/wave
#pragma unroll
    for (int it = 0; it < 4; ++it) {
      int chunk = wave + it * 4;
      int p = chunk * 1024 + lane * 16;
      int row = p >> 7;
      int colb = p & 127;
      int colb_g = colb ^ ((row & 7) << 4); // inverse-swizzle the SOURCE
      size_t goff = (size_t)(m0 + row) * strideA + (size_t)k0 * 2 + colb_g;
      __builtin_amdgcn_global_load_lds(
          (const __attribute__((address_space(1))) void*)((const char*)A + goff),
          (__attribute__((address_space(3))) void*)(As + chunk * 1024), 16, 0, 0);
    }
    // ---- stage B tile: 8 chunks, 2/wave
#pragma unroll
    for (int it = 0; it < 2; ++it) {
      int chunk = wave + it * 4;
      int p = chunk * 1024 + lane * 16;
      int row = p >> 7;
      int colb = p & 127;
      int colb_g = colb ^ ((row & 7) << 4);
      size_t goff = (size_t)(n0 + row) * strideA + (size_t)k0 * 2 + colb_g;
      __builtin_amdgcn_global_load_lds(
          (const __attribute__((address_space(1))) void*)((const char*)Bt + goff),
          (__attribute__((address_space(3))) void*)(Bs + chunk * 1024), 16, 0, 0);
    }
    __syncthreads();

    // ---- compute: 2 k-steps of 32
#pragma unroll
    for (int ks = 0; ks < 2; ++ks) {
      bf16x8 af[4], bfr[2];
      const int cb = (ks * 32 + ((lane >> 4) * 8)) * 2;
#pragma unroll
      for (int m = 0; m < 4; ++m) {
        int row = wr * 64 + m * 16 + (lane & 15);
        int addr = row * 128 + (cb ^ ((row & 7) << 4)); // swizzled read
        af[m] = *(const bf16x8*)(As + addr);
      }
#pragma unroll
      for (int n = 0; n < 2; ++n) {
        int row = wc * 32 + n * 16 + (lane & 15);
        int addr = row * 128 + (cb ^ ((row & 7) << 4));
        bfr[n] = *(const bf16x8*)(Bs + addr);
      }
#pragma unroll
      for (int m = 0; m < 4; ++m)
#pragma unroll
        for (int n = 0; n < 2; ++n)
          acc[m][n] = __builtin_amdgcn_mfma_f32_16x16x32_bf16(af[m], bfr[n], acc[m][n], 0, 0, 0);
    }
  }

  // ---- epilogue: C/D layout col=lane&15, row=(lane>>4)*4+i
#pragma unroll
  for (int m = 0; m < 4; ++m) {
#pragma unroll
    for (int n = 0; n < 2; ++n) {
      int col = n0 + wc * 32 + n * 16 + (lane & 15);
      float bv = bias1 ? bias1[col] : 0.f;
#pragma unroll
      for (int i = 0; i < 4; ++i) {
        int row = m0 + wr * 64 + m * 16 + ((lane >> 4) * 4) + i;
        float v = acc[m][n][i] + bv;
        if (bias2d) v += bias2d[(size_t)row * N + col];
        if (relu) v = fmaxf(v, 0.f);
        if (Cf) Cf[(size_t)row * N + col] = v;
        else Ch[(size_t)row * N + col] = __float2bfloat16(v);
      }
    }
  }
}

// ---------------- final layer: [B,128] fp32 x W4[128] + b4 -> out[B] fp32
__global__ void final_v4(const float* __restrict__ A3,
                         const float* __restrict__ W4,
                         const float* __restrict__ b4,
                         float* __restrict__ out) {
  int row = blockIdx.x * 4 + (threadIdx.x >> 6);
  int lane = threadIdx.x & 63;
  const float* a = A3 + (size_t)row * 128;
  float s = a[lane * 2] * W4[lane * 2] + a[lane * 2 + 1] * W4[lane * 2 + 1];
#pragma unroll
  for (int off = 32; off > 0; off >>= 1) s += __shfl_down(s, off);
  if (lane == 0) out[row] = s + b4[0];
}

extern "C" void kernel_launch(void* const* d_in, const int* in_sizes, int n_in,
                              void* d_out, int out_size, void* d_ws, size_t ws_size,
                              hipStream_t stream) {
  const float* numerical = (const float*)d_in[0];
  const int* cat = (const int*)d_in[1];
  const float* tables = (const float*)d_in[2];
  const float* W1 = (const float*)d_in[3];
  const float* b1 = (const float*)d_in[4];
  const float* W2 = (const float*)d_in[5];
  const float* b2 = (const float*)d_in[6];
  const float* W3 = (const float*)d_in[7];
  const float* b3 = (const float*)d_in[8];
  const float* W4 = (const float*)d_in[9];
  const float* b4 = (const float*)d_in[10];
  float* out = (float*)d_out;

  char* ws = (char*)d_ws;
  size_t off = 0;
  auto walloc = [&](size_t bytes) -> void* {
    void* p = ws + off;
    off = (off + bytes + 255) & ~(size_t)255;
    return p;
  };
  __hip_bfloat16* xh  = (__hip_bfloat16*)walloc((size_t)T_BATCH * T_DE * 2);  // 27.3MB
  __hip_bfloat16* w1t = (__hip_bfloat16*)walloc((size_t)512 * T_DE * 2);      // 3.4MB
  float*          c0  = (float*)walloc((size_t)T_BATCH * 512 * 4);            // 8MB
  __hip_bfloat16* a1  = (__hip_bfloat16*)walloc((size_t)T_BATCH * 512 * 2);
  __hip_bfloat16* w2t = (__hip_bfloat16*)walloc((size_t)256 * 512 * 2);
  __hip_bfloat16* a2  = (__hip_bfloat16*)walloc((size_t)T_BATCH * 256 * 2);
  __hip_bfloat16* w3t = (__hip_bfloat16*)walloc((size_t)128 * 256 * 2);
  float*          a3  = (float*)walloc((size_t)T_BATCH * 128 * 4);

  // weight prep (embedding rows of W1 only; numerical rows go to c0 in fp32)
  wtrans_v4<<<dim3(T_DE / 32, 512 / 32), dim3(32, 8), 0, stream>>>(W1, w1t, T_DE, 512);
  wtrans_v4<<<dim3(512 / 32, 256 / 32), dim3(32, 8), 0, stream>>>(W2, w2t, 512, 256);
  wtrans_v4<<<dim3(256 / 32, 128 / 32), dim3(32, 8), 0, stream>>>(W3, w3t, 256, 128);
  numbias_v4<<<T_BATCH, 256, 0, stream>>>(numerical, W1, b1, c0);

  // gather+pool (table-major dispatch for L3 locality)
  pool_v4<<<dim3(T_BATCH / 2, T_NUM_TABLES), dim3(T_WIDTH, 2), 0, stream>>>(tables, cat, xh);

  // MLP
  gemm_v4<<<dim3(T_BATCH / G_BM, 512 / G_BN), 256, 0, stream>>>(
      xh, w1t, nullptr, c0, a1, nullptr, T_BATCH, 512, T_DE, 1);
  gemm_v4<<<dim3(T_BATCH / G_BM, 256 / G_BN), 256, 0, stream>>>(
      a1, w2t, b2, nullptr, a2, nullptr, T_BATCH, 256, 512, 1);
  gemm_v4<<<dim3(T_BATCH / G_BM, 128 / G_BN), 256, 0, stream>>>(
      a2, w3t, b3, nullptr, nullptr, a3, T_BATCH, 128, 256, 1);
  final_v4<<<T_BATCH / 4, 256, 0, stream>>>(a3, W4, b4, out);
}

// Round 5
// 222.349 us; speedup vs baseline: 1.2503x; 1.1425x over previous
//
#include <hip/hip_runtime.h>
#include <hip/hip_bf16.h>

#define T_NUM_TABLES 26
#define T_NUM_ROWS 50000
#define T_WIDTH 128
#define T_BATCH 4096
#define T_NNZ 20
#define T_NUM_NUM 13
#define T_DE (T_NUM_TABLES * T_WIDTH) /* 3328 = 64*52 */

typedef __attribute__((ext_vector_type(4))) float f32x4;
typedef __attribute__((ext_vector_type(8))) short bf16x8;

// ================= prep: 3x weight transpose + numerical bias + out init =================
// jobs (1D grid): [0,1664) wtrans W1(3328x512), [1664,1792) W2(512x256),
// [1792,1824) W3(256x128), [1824, 1824+4096) numbias rows + out init.
__global__ void prep_v5(const float* __restrict__ W1, const float* __restrict__ W2,
                        const float* __restrict__ W3, const float* __restrict__ b1,
                        const float* __restrict__ b4, const float* __restrict__ num,
                        __hip_bfloat16* __restrict__ w1t, __hip_bfloat16* __restrict__ w2t,
                        __hip_bfloat16* __restrict__ w3t, float* __restrict__ c0,
                        float* __restrict__ out) {
  int bid = blockIdx.x;
  if (bid >= 1824) { // ---- numbias for batch row b
    int b = bid - 1824;
    __shared__ float snum[T_NUM_NUM];
    if (threadIdx.x < T_NUM_NUM) snum[threadIdx.x] = num[b * T_NUM_NUM + threadIdx.x];
    if (threadIdx.x == 0) out[b] = b4[0];
    __syncthreads();
#pragma unroll
    for (int rep = 0; rep < 2; ++rep) {
      int n = threadIdx.x + rep * 256;
      float acc = b1[n];
#pragma unroll
      for (int j = 0; j < T_NUM_NUM; ++j)
        acc += snum[j] * W1[(size_t)(T_DE + j) * 512 + n];
      c0[(size_t)b * 512 + n] = acc;
    }
    return;
  }
  // ---- transpose jobs
  const float* in;
  __hip_bfloat16* outt;
  int Kc, N, xb, yb;
  if (bid < 1664)      { in = W1; outt = w1t; Kc = 3328; N = 512; xb = bid % 104; yb = bid / 104; }
  else if (bid < 1792) { int r = bid - 1664; in = W2; outt = w2t; Kc = 512; N = 256; xb = r % 16; yb = r / 16; }
  else                 { int r = bid - 1792; in = W3; outt = w3t; Kc = 256; N = 128; xb = r % 8;  yb = r / 8;  }
  int tx = threadIdx.x & 31, ty = threadIdx.x >> 5;
  __shared__ float tile[32][33];
  int kb = xb * 32, nb = yb * 32;
  for (int r = ty; r < 32; r += 8) tile[r][tx] = in[(size_t)(kb + r) * N + nb + tx];
  __syncthreads();
  for (int r = ty; r < 32; r += 8) outt[(size_t)(nb + r) * Kc + kb + tx] = __float2bfloat16(tile[tx][r]);
}

// ================= gather + pool (float4 gathers) -> bf16 x[B][3328] =================
__global__ void pool_v5(const float* __restrict__ tables,
                        const int* __restrict__ cat,
                        __hip_bfloat16* __restrict__ xh) {
  __shared__ int sidx[8][T_NNZ];
  const int b0 = blockIdx.x * 8;
  const int t = blockIdx.y;
  const int tx = threadIdx.x & 31; // col quad
  const int ty = threadIdx.x >> 5; // batch elem within block
  if (threadIdx.x < 8 * T_NNZ) {
    int y = threadIdx.x / T_NNZ, j = threadIdx.x % T_NNZ;
    sidx[y][j] = cat[((size_t)t * T_BATCH + b0 + y) * T_NNZ + j];
  }
  __syncthreads();
  const f32x4* tb = (const f32x4*)(tables + (size_t)t * T_NUM_ROWS * T_WIDTH);
  f32x4 acc = {0.f, 0.f, 0.f, 0.f};
#pragma unroll
  for (int j = 0; j < T_NNZ; ++j) {
    acc += tb[(size_t)sidx[ty][j] * 32 + tx];
  }
  ushort4 u;
  {
    __hip_bfloat16 h0 = __float2bfloat16(acc[0]), h1 = __float2bfloat16(acc[1]);
    __hip_bfloat16 h2 = __float2bfloat16(acc[2]), h3 = __float2bfloat16(acc[3]);
    u.x = *(unsigned short*)&h0; u.y = *(unsigned short*)&h1;
    u.z = *(unsigned short*)&h2; u.w = *(unsigned short*)&h3;
  }
  *(ushort4*)(&xh[(size_t)(b0 + ty) * T_DE + t * T_WIDTH + tx * 4]) = u;
}

// ================= bf16 MFMA GEMM, templated tile =================
// 4 waves in 2x2; wave-tile (BM/2)x(BN/2); 16x16x32 frags, MR=BM/32, NR=BN/32.
// MODE 0: write bf16 Ch (bias1 and/or bias2d). MODE 2: fused final dot -> atomicAdd out.
template <int BM, int BN, int RELU, int MODE>
__global__ __launch_bounds__(256, 2) void gemm_v5(
    const __hip_bfloat16* __restrict__ A,   // [M][Kp]
    const __hip_bfloat16* __restrict__ Bt,  // [N][Kp]
    const float* __restrict__ bias1,        // [N] or null
    const float* __restrict__ bias2d,       // [M][N] or null
    const float* __restrict__ W4,           // MODE 2
    __hip_bfloat16* __restrict__ Ch,        // MODE 0
    float* __restrict__ outv,               // MODE 2
    int M, int N, int Kp) {
  constexpr int MR = BM / 32, NR = BN / 32;
  __shared__ char smem[BM * 128 + BN * 128];
  char* As = smem;
  char* Bs = smem + BM * 128;

  const int tid = threadIdx.x;
  const int wave = tid >> 6;
  const int lane = tid & 63;
  const int m0 = blockIdx.x * BM;
  const int n0 = blockIdx.y * BN;
  const int wr = wave >> 1;
  const int wc = wave & 1;

  f32x4 acc[MR][NR] = {};
  const size_t strideA = (size_t)Kp * 2;

  for (int k0 = 0; k0 < Kp; k0 += 64) {
    __syncthreads();
#pragma unroll
    for (int it = 0; it < BM / 32; ++it) {
      int chunk = wave + it * 4; // BM/8 chunks of 1024B
      int p = chunk * 1024 + lane * 16;
      int row = p >> 7;
      int colb = p & 127;
      int colb_g = colb ^ ((row & 7) << 4); // inverse-swizzle SOURCE
      size_t goff = (size_t)(m0 + row) * strideA + (size_t)k0 * 2 + colb_g;
      __builtin_amdgcn_global_load_lds(
          (const __attribute__((address_space(1))) void*)((const char*)A + goff),
          (__attribute__((address_space(3))) void*)(As + chunk * 1024), 16, 0, 0);
    }
#pragma unroll
    for (int it = 0; it < BN / 32; ++it) {
      int chunk = wave + it * 4;
      int p = chunk * 1024 + lane * 16;
      int row = p >> 7;
      int colb = p & 127;
      int colb_g = colb ^ ((row & 7) << 4);
      size_t goff = (size_t)(n0 + row) * strideA + (size_t)k0 * 2 + colb_g;
      __builtin_amdgcn_global_load_lds(
          (const __attribute__((address_space(1))) void*)((const char*)Bt + goff),
          (__attribute__((address_space(3))) void*)(Bs + chunk * 1024), 16, 0, 0);
    }
    __syncthreads();

#pragma unroll
    for (int ks = 0; ks < 2; ++ks) {
      bf16x8 af[MR], bfr[NR];
      const int cb = (ks * 32 + ((lane >> 4) * 8)) * 2;
#pragma unroll
      for (int m = 0; m < MR; ++m) {
        int row = wr * (BM / 2) + m * 16 + (lane & 15);
        int addr = row * 128 + (cb ^ ((row & 7) << 4));
        af[m] = *(const bf16x8*)(As + addr);
      }
#pragma unroll
      for (int n = 0; n < NR; ++n) {
        int row = wc * (BN / 2) + n * 16 + (lane & 15);
        int addr = row * 128 + (cb ^ ((row & 7) << 4));
        bfr[n] = *(const bf16x8*)(Bs + addr);
      }
#pragma unroll
      for (int m = 0; m < MR; ++m)
#pragma unroll
        for (int n = 0; n < NR; ++n)
          acc[m][n] = __builtin_amdgcn_mfma_f32_16x16x32_bf16(af[m], bfr[n], acc[m][n], 0, 0, 0);
    }
  }

  // epilogue: C/D layout col=lane&15, row=(lane>>4)*4+i
#pragma unroll
  for (int m = 0; m < MR; ++m) {
#pragma unroll
    for (int n = 0; n < NR; ++n) {
      int col = n0 + wc * (BN / 2) + n * 16 + (lane & 15);
      float bv = bias1 ? bias1[col] : 0.f;
      float w4c = (MODE == 2) ? W4[col] : 0.f;
      float dot[4];
#pragma unroll
      for (int i = 0; i < 4; ++i) {
        int row = m0 + wr * (BM / 2) + m * 16 + ((lane >> 4) * 4) + i;
        float v = acc[m][n][i] + bv;
        if (bias2d) v += bias2d[(size_t)row * N + col];
        if (RELU) v = fmaxf(v, 0.f);
        if (MODE == 0) {
          Ch[(size_t)row * N + col] = __float2bfloat16(v);
        } else {
          dot[i] = v * w4c;
        }
      }
      if (MODE == 2) {
#pragma unroll
        for (int i = 0; i < 4; ++i) {
#pragma unroll
          for (int mask = 1; mask < 16; mask <<= 1) dot[i] += __shfl_xor(dot[i], mask);
        }
        if ((lane & 15) == 0) {
          int rowb = m0 + wr * (BM / 2) + m * 16 + ((lane >> 4) * 4);
#pragma unroll
          for (int i = 0; i < 4; ++i) atomicAdd(&outv[rowb + i], dot[i]);
        }
      }
    }
  }
}

extern "C" void kernel_launch(void* const* d_in, const int* in_sizes, int n_in,
                              void* d_out, int out_size, void* d_ws, size_t ws_size,
                              hipStream_t stream) {
  const float* numerical = (const float*)d_in[0];
  const int* cat = (const int*)d_in[1];
  const float* tables = (const float*)d_in[2];
  const float* W1 = (const float*)d_in[3];
  const float* b1 = (const float*)d_in[4];
  const float* W2 = (const float*)d_in[5];
  const float* b2 = (const float*)d_in[6];
  const float* W3 = (const float*)d_in[7];
  const float* b3 = (const float*)d_in[8];
  const float* W4 = (const float*)d_in[9];
  const float* b4 = (const float*)d_in[10];
  float* out = (float*)d_out;

  char* ws = (char*)d_ws;
  size_t off = 0;
  auto walloc = [&](size_t bytes) -> void* {
    void* p = ws + off;
    off = (off + bytes + 255) & ~(size_t)255;
    return p;
  };
  __hip_bfloat16* xh  = (__hip_bfloat16*)walloc((size_t)T_BATCH * T_DE * 2);
  __hip_bfloat16* w1t = (__hip_bfloat16*)walloc((size_t)512 * T_DE * 2);
  float*          c0  = (float*)walloc((size_t)T_BATCH * 512 * 4);
  __hip_bfloat16* a1  = (__hip_bfloat16*)walloc((size_t)T_BATCH * 512 * 2);
  __hip_bfloat16* w2t = (__hip_bfloat16*)walloc((size_t)256 * 512 * 2);
  __hip_bfloat16* a2  = (__hip_bfloat16*)walloc((size_t)T_BATCH * 256 * 2);
  __hip_bfloat16* w3t = (__hip_bfloat16*)walloc((size_t)128 * 256 * 2);

  prep_v5<<<1824 + T_BATCH, 256, 0, stream>>>(W1, W2, W3, b1, b4, numerical,
                                              w1t, w2t, w3t, c0, out);
  pool_v5<<<dim3(T_BATCH / 8, T_NUM_TABLES), 256, 0, stream>>>(tables, cat, xh);

  gemm_v5<64, 64, 1, 0><<<dim3(T_BATCH / 64, 512 / 64), 256, 0, stream>>>(
      xh, w1t, nullptr, c0, nullptr, a1, nullptr, T_BATCH, 512, T_DE);
  gemm_v5<64, 32, 1, 0><<<dim3(T_BATCH / 64, 256 / 32), 256, 0, stream>>>(
      a1, w2t, b2, nullptr, nullptr, a2, nullptr, T_BATCH, 256, 512);
  gemm_v5<64, 32, 1, 2><<<dim3(T_BATCH / 64, 128 / 32), 256, 0, stream>>>(
      a2, w3t, b3, nullptr, W4, nullptr, out, T_BATCH, 128, 256);
}

// Round 6
// 205.831 us; speedup vs baseline: 1.3506x; 1.0802x over previous
//
#include <hip/hip_runtime.h>
#include <hip/hip_bf16.h>

#define T_NUM_TABLES 26
#define T_NUM_ROWS 50000
#define T_WIDTH 128
#define T_BATCH 4096
#define T_NNZ 20
#define T_NUM_NUM 13
#define T_DE (T_NUM_TABLES * T_WIDTH) /* 3328 = 64*52 */

typedef __attribute__((ext_vector_type(4))) float f32x4;
typedef __attribute__((ext_vector_type(8))) short bf16x8;

// ================= fused pool + prep =================
// bid [0, 13312): pool (512 batch-groups x 26 tables, table-major)
// bid [13312, 15136): weight transposes (W1:1664, W2:128, W3:32)
// bid [15136, 19232): numerical-bias rows + out init
#define PJ_POOL (512 * T_NUM_TABLES)         /* 13312 */
#define PJ_WT (PJ_POOL + 1664 + 128 + 32)    /* 15136 */
#define PJ_TOTAL (PJ_WT + T_BATCH)           /* 19232 */

__global__ void poolprep_v6(const float* __restrict__ tables,
                            const int* __restrict__ cat,
                            const float* __restrict__ W1, const float* __restrict__ W2,
                            const float* __restrict__ W3, const float* __restrict__ b1,
                            const float* __restrict__ b4, const float* __restrict__ num,
                            __hip_bfloat16* __restrict__ xh,
                            __hip_bfloat16* __restrict__ w1t, __hip_bfloat16* __restrict__ w2t,
                            __hip_bfloat16* __restrict__ w3t, float* __restrict__ c0,
                            float* __restrict__ out) {
  __shared__ int sidx[8][T_NNZ];
  __shared__ float tile[32][33];
  __shared__ float snum[T_NUM_NUM];
  const int bid = blockIdx.x;

  if (bid < PJ_POOL) { // ---------------- pool: float4 gathers
    const int g = bid & 511;       // batch group (x-fastest => table-major order)
    const int t = bid >> 9;        // table
    const int b0 = g * 8;
    const int tx = threadIdx.x & 31;
    const int ty = threadIdx.x >> 5;
    if (threadIdx.x < 8 * T_NNZ) {
      int y = threadIdx.x / T_NNZ, j = threadIdx.x % T_NNZ;
      sidx[y][j] = cat[((size_t)t * T_BATCH + b0 + y) * T_NNZ + j];
    }
    __syncthreads();
    const f32x4* tb = (const f32x4*)(tables + (size_t)t * T_NUM_ROWS * T_WIDTH);
    f32x4 acc = {0.f, 0.f, 0.f, 0.f};
#pragma unroll
    for (int j = 0; j < T_NNZ; ++j) acc += tb[(size_t)sidx[ty][j] * 32 + tx];
    ushort4 u;
    {
      __hip_bfloat16 h0 = __float2bfloat16(acc[0]), h1 = __float2bfloat16(acc[1]);
      __hip_bfloat16 h2 = __float2bfloat16(acc[2]), h3 = __float2bfloat16(acc[3]);
      u.x = *(unsigned short*)&h0; u.y = *(unsigned short*)&h1;
      u.z = *(unsigned short*)&h2; u.w = *(unsigned short*)&h3;
    }
    *(ushort4*)(&xh[(size_t)(b0 + ty) * T_DE + t * T_WIDTH + tx * 4]) = u;
    return;
  }

  if (bid < PJ_WT) { // ---------------- weight transpose + bf16 cast
    int r = bid - PJ_POOL;
    const float* in;
    __hip_bfloat16* outt;
    int Kc, N, xb, yb;
    if (r < 1664)      { in = W1; outt = w1t; Kc = 3328; N = 512; xb = r % 104; yb = r / 104; }
    else if (r < 1792) { r -= 1664; in = W2; outt = w2t; Kc = 512; N = 256; xb = r % 16; yb = r / 16; }
    else               { r -= 1792; in = W3; outt = w3t; Kc = 256; N = 128; xb = r % 8;  yb = r / 8;  }
    int tx = threadIdx.x & 31, ty = threadIdx.x >> 5;
    int kb = xb * 32, nb = yb * 32;
    for (int rr = ty; rr < 32; rr += 8) tile[rr][tx] = in[(size_t)(kb + rr) * N + nb + tx];
    __syncthreads();
    for (int rr = ty; rr < 32; rr += 8)
      outt[(size_t)(nb + rr) * Kc + kb + tx] = __float2bfloat16(tile[tx][rr]);
    return;
  }

  { // ---------------- numerical bias (exact fp32) + out init
    int b = bid - PJ_WT;
    if (threadIdx.x < T_NUM_NUM) snum[threadIdx.x] = num[b * T_NUM_NUM + threadIdx.x];
    if (threadIdx.x == 0) out[b] = b4[0];
    __syncthreads();
#pragma unroll
    for (int rep = 0; rep < 2; ++rep) {
      int n = threadIdx.x + rep * 256;
      float acc = b1[n];
#pragma unroll
      for (int j = 0; j < T_NUM_NUM; ++j)
        acc += snum[j] * W1[(size_t)(T_DE + j) * 512 + n];
      c0[(size_t)b * 512 + n] = acc;
    }
  }
}

// ================= bf16 MFMA GEMM, 2-phase double-buffered =================
// 4 waves 2x2; per-wave (BM/2)x(BN/2); 16x16x32 frags.
// MODE 0: bf16 out (bias1 and/or bias2d). MODE 2: fused final dot -> atomicAdd out.
template <int BM, int BN, int RELU, int MODE>
__global__ __launch_bounds__(256, 2) void gemm_v6(
    const __hip_bfloat16* __restrict__ A,   // [M][Kp]
    const __hip_bfloat16* __restrict__ Bt,  // [N][Kp]
    const float* __restrict__ bias1,        // [N] or null
    const float* __restrict__ bias2d,       // [M][N] or null
    const float* __restrict__ W4,           // MODE 2
    __hip_bfloat16* __restrict__ Ch,        // MODE 0
    float* __restrict__ outv,               // MODE 2
    int M, int N, int Kp) {
  constexpr int MR = BM / 32, NR = BN / 32;
  constexpr int BUFB = BM * 128 + BN * 128;
  __shared__ char smem[2 * BUFB];

  const int tid = threadIdx.x;
  const int wave = tid >> 6;
  const int lane = tid & 63;
  const int m0 = blockIdx.x * BM;
  const int n0 = blockIdx.y * BN;
  const int wr = wave >> 1;
  const int wc = wave & 1;

  f32x4 acc[MR][NR] = {};
  const size_t strideA = (size_t)Kp * 2;

  auto stage = [&](int k0, int buf) {
    char* As = smem + buf * BUFB;
    char* Bs = As + BM * 128;
#pragma unroll
    for (int it = 0; it < BM / 32; ++it) {
      int chunk = wave + it * 4;
      int p = chunk * 1024 + lane * 16;
      int row = p >> 7, colb = p & 127;
      int colb_g = colb ^ ((row & 7) << 4); // inverse-swizzle SOURCE
      size_t goff = (size_t)(m0 + row) * strideA + (size_t)k0 * 2 + colb_g;
      __builtin_amdgcn_global_load_lds(
          (const __attribute__((address_space(1))) void*)((const char*)A + goff),
          (__attribute__((address_space(3))) void*)(As + chunk * 1024), 16, 0, 0);
    }
#pragma unroll
    for (int it = 0; it < BN / 32; ++it) {
      int chunk = wave + it * 4;
      int p = chunk * 1024 + lane * 16;
      int row = p >> 7, colb = p & 127;
      int colb_g = colb ^ ((row & 7) << 4);
      size_t goff = (size_t)(n0 + row) * strideA + (size_t)k0 * 2 + colb_g;
      __builtin_amdgcn_global_load_lds(
          (const __attribute__((address_space(1))) void*)((const char*)Bt + goff),
          (__attribute__((address_space(3))) void*)(Bs + chunk * 1024), 16, 0, 0);
    }
  };

  const int nt = Kp >> 6;
  stage(0, 0);
  __syncthreads(); // drains vmcnt -> buf0 ready
  int cur = 0;
  for (int t = 0; t < nt; ++t) {
    if (t + 1 < nt) stage((t + 1) << 6, cur ^ 1); // issue next-tile loads FIRST
    char* As = smem + cur * BUFB;
    char* Bs = As + BM * 128;
#pragma unroll
    for (int ks = 0; ks < 2; ++ks) {
      bf16x8 af[MR], bfr[NR];
      const int cb = (ks * 32 + ((lane >> 4) * 8)) * 2;
#pragma unroll
      for (int m = 0; m < MR; ++m) {
        int row = wr * (BM / 2) + m * 16 + (lane & 15);
        int addr = row * 128 + (cb ^ ((row & 7) << 4));
        af[m] = *(const bf16x8*)(As + addr);
      }
#pragma unroll
      for (int n = 0; n < NR; ++n) {
        int row = wc * (BN / 2) + n * 16 + (lane & 15);
        int addr = row * 128 + (cb ^ ((row & 7) << 4));
        bfr[n] = *(const bf16x8*)(Bs + addr);
      }
#pragma unroll
      for (int m = 0; m < MR; ++m)
#pragma unroll
        for (int n = 0; n < NR; ++n)
          acc[m][n] = __builtin_amdgcn_mfma_f32_16x16x32_bf16(af[m], bfr[n], acc[m][n], 0, 0, 0);
    }
    __syncthreads(); // one barrier per K-tile: drains next-tile loads after compute
    cur ^= 1;
  }

  // epilogue: C/D layout col=lane&15, row=(lane>>4)*4+i
#pragma unroll
  for (int m = 0; m < MR; ++m) {
#pragma unroll
    for (int n = 0; n < NR; ++n) {
      int col = n0 + wc * (BN / 2) + n * 16 + (lane & 15);
      float bv = bias1 ? bias1[col] : 0.f;
      float w4c = (MODE == 2) ? W4[col] : 0.f;
      float dot[4];
#pragma unroll
      for (int i = 0; i < 4; ++i) {
        int row = m0 + wr * (BM / 2) + m * 16 + ((lane >> 4) * 4) + i;
        float v = acc[m][n][i] + bv;
        if (bias2d) v += bias2d[(size_t)row * N + col];
        if (RELU) v = fmaxf(v, 0.f);
        if (MODE == 0) {
          Ch[(size_t)row * N + col] = __float2bfloat16(v);
        } else {
          dot[i] = v * w4c;
        }
      }
      if (MODE == 2) {
#pragma unroll
        for (int i = 0; i < 4; ++i) {
#pragma unroll
          for (int mask = 1; mask < 16; mask <<= 1) dot[i] += __shfl_xor(dot[i], mask);
        }
        if ((lane & 15) == 0) {
          int rowb = m0 + wr * (BM / 2) + m * 16 + ((lane >> 4) * 4);
#pragma unroll
          for (int i = 0; i < 4; ++i) atomicAdd(&outv[rowb + i], dot[i]);
        }
      }
    }
  }
}

extern "C" void kernel_launch(void* const* d_in, const int* in_sizes, int n_in,
                              void* d_out, int out_size, void* d_ws, size_t ws_size,
                              hipStream_t stream) {
  const float* numerical = (const float*)d_in[0];
  const int* cat = (const int*)d_in[1];
  const float* tables = (const float*)d_in[2];
  const float* W1 = (const float*)d_in[3];
  const float* b1 = (const float*)d_in[4];
  const float* W2 = (const float*)d_in[5];
  const float* b2 = (const float*)d_in[6];
  const float* W3 = (const float*)d_in[7];
  const float* b3 = (const float*)d_in[8];
  const float* W4 = (const float*)d_in[9];
  const float* b4 = (const float*)d_in[10];
  float* out = (float*)d_out;

  char* ws = (char*)d_ws;
  size_t off = 0;
  auto walloc = [&](size_t bytes) -> void* {
    void* p = ws + off;
    off = (off + bytes + 255) & ~(size_t)255;
    return p;
  };
  __hip_bfloat16* xh  = (__hip_bfloat16*)walloc((size_t)T_BATCH * T_DE * 2);
  __hip_bfloat16* w1t = (__hip_bfloat16*)walloc((size_t)512 * T_DE * 2);
  float*          c0  = (float*)walloc((size_t)T_BATCH * 512 * 4);
  __hip_bfloat16* a1  = (__hip_bfloat16*)walloc((size_t)T_BATCH * 512 * 2);
  __hip_bfloat16* w2t = (__hip_bfloat16*)walloc((size_t)256 * 512 * 2);
  __hip_bfloat16* a2  = (__hip_bfloat16*)walloc((size_t)T_BATCH * 256 * 2);
  __hip_bfloat16* w3t = (__hip_bfloat16*)walloc((size_t)128 * 256 * 2);

  poolprep_v6<<<PJ_TOTAL, 256, 0, stream>>>(tables, cat, W1, W2, W3, b1, b4, numerical,
                                            xh, w1t, w2t, w3t, c0, out);

  gemm_v6<64, 64, 1, 0><<<dim3(T_BATCH / 64, 512 / 64), 256, 0, stream>>>(
      xh, w1t, nullptr, c0, nullptr, a1, nullptr, T_BATCH, 512, T_DE);
  gemm_v6<64, 32, 1, 0><<<dim3(T_BATCH / 64, 256 / 32), 256, 0, stream>>>(
      a1, w2t, b2, nullptr, nullptr, a2, nullptr, T_BATCH, 256, 512);
  gemm_v6<64, 32, 1, 2><<<dim3(T_BATCH / 64, 128 / 32), 256, 0, stream>>>(
      a2, w3t, b3, nullptr, W4, nullptr, out, T_BATCH, 128, 256);
}